// Round 6
// baseline (451.874 us; speedup 1.0000x reference)
//
#include <hip/hip_runtime.h>

// CapsNet dynamic routing, B=256, P=2048, C=10, OUT=16, IN=8, 3 iters.
// R12 = R11 (scalar-pipe W, single-pass, reg-resident v/uh/acc) + occupancy.
// R11 diagnosis: GRID=512 -> exactly 2 blocks/CU (grid-capped); each wave
// serializes on s_load batches (320 W floats/p through ~112 SGPRs = ~8
// load-use chains x ~250cy vs 640cy FMA issue -> VALUBusy 18%). MODE0 (no
// barriers/softmax) ran identical 113us -> pure latency x occupancy problem.
// Fix: PPB 16->8 (GRID 1024 = 4 blocks/CU) + LDS 41KB->20.6KB (tail stages
// sAcc in 2 rounds of 32 b) so LDS never caps; launch_bounds(256,4) floor.
// Mapping (unchanged): wave g=(h,oh), lane=b_l (BT=64). W slice per (p,wave)
// wave-uniform, pre-permuted contiguous by k_perm -> s_load operands, zero
// LDS/vector traffic for W. Softmax: 5 partial logits through dbuf lgx
// (stride 5, conflict-free, one barrier per p), then all-10 softmax
// per-thread. v per-thread from sPrev (regs). s-reduce: arena stage
// (stride 161) -> coalesced fp32 atomics, 2 rounds of 32 b.
// Passes: K<0>: s1=sum_p uhat; K<1>: v1=squash(.1*s1), lg2=uhat.v1 -> global,
// s2+=softmax(lg2)*uhat; K<2>: v2=squash(s2), lg3=lg2+uhat.v2, s3+=...;
// k_out: squash(s3).

#define Bn 256
#define Pn 2048
#define Cn 10
#define On 16
#define In 8
#define ROW 160
#define BT 64
#define PPB 8
#define TPB 256
#define NBT (Bn / BT)     // 4
#define NPT (Pn / PPB)    // 256
#define GRID (NBT * NPT)  // 1024 -> 4 blocks/CU

// ---- one-time W permutation: Wp[p][g][kc][o][i], g = h*2+oh.
// Per (p, wave) slice = 320 contiguous floats -> s_load friendly.
__global__ __launch_bounds__(256) void k_perm(const float* __restrict__ W,
                                              float* __restrict__ Wp) {
  const int p = blockIdx.x;
  const float* src = W + (size_t)p * 1280;
  float* dst = Wp + (size_t)p * 1280;
#pragma unroll
  for (int r = 0; r < 5; ++r) {
    const int w = threadIdx.x + 256 * r;
    const int g = w / 320, rm = w - 320 * g;
    const int kc = rm >> 6, r2 = rm & 63;
    const int o = r2 >> 3, i = r2 & 7;
    const int h = g >> 1, oh = g & 1;
    dst[w] = src[((h * 5 + kc) * 16 + oh * 8 + o) * 8 + i];
  }
}

template <int MODE>
__global__ __launch_bounds__(TPB, 4) void k_cap(const float* __restrict__ u,
                                                const float* __restrict__ Wp,
                                                const float* __restrict__ sPrev,
                                                float* __restrict__ sOut,
                                                float* __restrict__ lg) {
  // arena: main loop = lgx[2][4g][64b][5] (2560 floats); tail = sAcc[32][161]
  __shared__ float arena[32 * 161]; // 20608 B -> LDS never the occupancy cap
  const int x = blockIdx.x;
  const int bt = x >> 8;   // 4 b-tiles
  const int pt = x & 255;  // 256 p-tiles; bt-sharers of a p-tile on one XCD
  const int tid = threadIdx.x;
  const int g = __builtin_amdgcn_readfirstlane(tid >> 6); // wave id = h*2+oh
  const int h = g >> 1, oh = g & 1;
  const int b_l = tid & 63;
  const int b = bt * BT + b_l;
  const int p0 = pt * PPB;

  // wave-uniform W base -> scalar loads
  const float* wp_s = Wp + ((size_t)p0 * 4 + g) * 320;

  // ---- v slice in registers (per-thread squash of sPrev; once per dispatch)
  float v[5][8];
  if (MODE >= 1) {
    const float scale = (MODE == 1) ? 0.1f : 1.0f;
    const float4* sp = reinterpret_cast<const float4*>(sPrev + (size_t)b * ROW);
#pragma unroll
    for (int kc = 0; kc < 5; ++kc) {
      const int c = h * 5 + kc;
      const float4 q0 = sp[c * 4 + 0], q1 = sp[c * 4 + 1];
      const float4 q2 = sp[c * 4 + 2], q3 = sp[c * 4 + 3];
      float sq = q0.x * q0.x + q0.y * q0.y + q0.z * q0.z + q0.w * q0.w;
      sq += q1.x * q1.x + q1.y * q1.y + q1.z * q1.z + q1.w * q1.w;
      sq += q2.x * q2.x + q2.y * q2.y + q2.z * q2.z + q2.w * q2.w;
      sq += q3.x * q3.x + q3.y * q3.y + q3.z * q3.z + q3.w * q3.w;
      sq *= scale * scale;
      const float fac = scale * (sq / (1.f + sq)) / sqrtf(sq + 1e-9f);
      const float4 qa = oh ? q2 : q0;
      const float4 qb = oh ? q3 : q1;
      v[kc][0] = fac * qa.x; v[kc][1] = fac * qa.y;
      v[kc][2] = fac * qa.z; v[kc][3] = fac * qa.w;
      v[kc][4] = fac * qb.x; v[kc][5] = fac * qb.y;
      v[kc][6] = fac * qb.z; v[kc][7] = fac * qb.w;
    }
  }

  float acc[5][8];
#pragma unroll
  for (int kc = 0; kc < 5; ++kc)
#pragma unroll
    for (int o = 0; o < 8; ++o) acc[kc][o] = 0.f;

  const float* urow = u + ((size_t)b * Pn + p0) * In;
  float4 cua, cub;
  {
    const float4* up = reinterpret_cast<const float4*>(urow);
    cua = up[0];
    cub = up[1];
  }

  for (int ip = 0; ip < PPB; ++ip) {
    // prefetch next p's u (named regs, static)
    float4 nua = cua, nub = cub;
    if (ip + 1 < PPB) {
      const float4* up = reinterpret_cast<const float4*>(urow + (ip + 1) * In);
      nua = up[0];
      nub = up[1];
    }
    const int p = p0 + ip;
    float lf[10];
    if (MODE == 2) { // issue early; latency hides under the dot block
      const float* lrow = lg + ((size_t)p * Bn + b) * Cn;
#pragma unroll
      for (int c = 0; c < 10; ++c) lf[c] = lrow[c];
    } else if (MODE == 1) {
#pragma unroll
      for (int c = 0; c < 10; ++c) lf[c] = 0.f;
    }
    const float uu[8] = {cua.x, cua.y, cua.z, cua.w, cub.x, cub.y, cub.z, cub.w};
    const float* wq = wp_s + ip * 1280; // scalar pointer

    float uh[5][8];
#pragma unroll
    for (int kc = 0; kc < 5; ++kc)
#pragma unroll
      for (int o = 0; o < 8; ++o) {
        const float* w8 = wq + kc * 64 + o * 8; // s_load operands
        float d = w8[0] * uu[0];
#pragma unroll
        for (int i = 1; i < 8; ++i) d = __builtin_fmaf(w8[i], uu[i], d);
        uh[kc][o] = d;
      }

    if (MODE == 0) {
#pragma unroll
      for (int kc = 0; kc < 5; ++kc)
#pragma unroll
        for (int o = 0; o < 8; ++o) acc[kc][o] += uh[kc][o];
    } else {
      // partial logits for this (h,oh) quarter
      float lp[5];
#pragma unroll
      for (int kc = 0; kc < 5; ++kc) {
        float ls = 0.f;
#pragma unroll
        for (int o = 0; o < 8; ++o) ls = __builtin_fmaf(uh[kc][o], v[kc][o], ls);
        lp[kc] = ls;
      }
      // exchange: lgx[(ip&1)][g][b_l][5]; stride 5 -> conflict-free
      float* lx = arena + (ip & 1) * 1280;
#pragma unroll
      for (int kc = 0; kc < 5; ++kc) lx[(g * 64 + b_l) * 5 + kc] = lp[kc];
      __syncthreads(); // double-buffered -> one barrier per p
#pragma unroll
      for (int c = 0; c < 10; ++c) {
        const int hh = c / 5, cc = c - 5 * (c / 5); // static after unroll
        lf[c] += lx[((hh * 2 + 0) * 64 + b_l) * 5 + cc] +
                 lx[((hh * 2 + 1) * 64 + b_l) * 5 + cc];
      }
      if (MODE == 1) {
        if (g == 0) { // wave-uniform branch; coalesced 40B/lane
          float* lrow = lg + ((size_t)p * Bn + b) * Cn;
#pragma unroll
          for (int c = 0; c < 10; ++c) lrow[c] = lf[c];
        }
      }
      // softmax over all 10 in-thread (redundant x4, cheap)
      float m = lf[0];
#pragma unroll
      for (int c = 1; c < 10; ++c) m = fmaxf(m, lf[c]);
      float ss = 0.f;
#pragma unroll
      for (int c = 0; c < 10; ++c) {
        lf[c] = __expf(lf[c] - m);
        ss += lf[c];
      }
      const float inv = 1.f / ss;
#pragma unroll
      for (int kc = 0; kc < 5; ++kc) {
        const float cv = lf[h * 5 + kc] * inv;
#pragma unroll
        for (int o = 0; o < 8; ++o)
          acc[kc][o] = __builtin_fmaf(cv, uh[kc][o], acc[kc][o]);
      }
    }
    cua = nua;
    cub = nub;
  }

  // ---- tail: 2 rounds of 32 b: stage (stride 161, conflict-free) + atomics
  __syncthreads(); // last lgx reads done before arena reuse
  float* sA = arena;
#pragma unroll
  for (int rnd = 0; rnd < 2; ++rnd) {
    if ((b_l >> 5) == rnd) {
      const int bl = b_l & 31;
#pragma unroll
      for (int kc = 0; kc < 5; ++kc)
#pragma unroll
        for (int o = 0; o < 8; ++o)
          sA[bl * 161 + (h * 5 + kc) * 16 + oh * 8 + o] = acc[kc][o];
    }
    __syncthreads();
#pragma unroll
    for (int r = 0; r < 20; ++r) {
      const int gi = tid + 256 * r; // 5120 cells, consecutive addresses
      const int bl = gi / 160, rem = gi - 160 * bl;
      atomicAdd(&sOut[(size_t)(bt * BT + rnd * 32 + bl) * ROW + rem],
                sA[bl * 161 + rem]);
    }
    if (rnd == 0) __syncthreads(); // reads done before round-1 overwrites
  }
}

__global__ __launch_bounds__(256) void k_out(const float* __restrict__ s,
                                             float* __restrict__ out) {
  const int gi = blockIdx.x * 256 + threadIdx.x; // [0, 2560) = (b,c)
  const int b = gi / 10, c = gi - 10 * b;
  const float* sp = s + (size_t)b * ROW + c * 16;
  float sq = 0.f;
#pragma unroll
  for (int o = 0; o < On; ++o) { const float xx = sp[o]; sq += xx * xx; }
  const float fac = (sq / (1.f + sq)) / sqrtf(sq + 1e-9f);
  float* op = out + (size_t)b * ROW + c * 16;
#pragma unroll
  for (int o = 0; o < On; ++o) op[o] = fac * sp[o];
}

extern "C" void kernel_launch(void* const* d_in, const int* in_sizes, int n_in,
                              void* d_out, int out_size, void* d_ws, size_t ws_size,
                              hipStream_t stream) {
  (void)in_sizes; (void)n_in; (void)out_size;
  const float* u = (const float*)d_in[0];
  const float* W = (const float*)d_in[1];
  float* out = (float*)d_out;
  float* s1 = (float*)d_ws;              // [256][160] fp32
  float* s2 = s1 + (size_t)Bn * ROW;
  float* s3 = s2 + (size_t)Bn * ROW;
  float* lg = s3 + (size_t)Bn * ROW;     // [2048][256][10] fp32, 21MB
  float* Wp = lg + (size_t)Pn * Bn * Cn; // permuted W, 10.5MB
  const size_t need = ((size_t)3 * Bn * ROW + (size_t)Pn * Bn * Cn +
                       (size_t)Pn * Cn * On * In) * sizeof(float);
  if (ws_size < need) return;
  hipMemsetAsync(d_ws, 0, (size_t)3 * Bn * ROW * sizeof(float), stream);
  k_perm<<<Pn, 256, 0, stream>>>(W, Wp);
  k_cap<0><<<GRID, TPB, 0, stream>>>(u, Wp, s1, s1, lg);
  k_cap<1><<<GRID, TPB, 0, stream>>>(u, Wp, s1, s2, lg);
  k_cap<2><<<GRID, TPB, 0, stream>>>(u, Wp, s2, s3, lg);
  k_out<<<10, 256, 0, stream>>>(s3, out);
}

// Round 7
// 306.418 us; speedup vs baseline: 1.4747x; 1.4747x over previous
//
#include <hip/hip_runtime.h>

// CapsNet dynamic routing, B=256, P=2048, C=10, OUT=16, IN=8, 3 iters.
// R13 = R12 geometry with R11's regalloc. R12's regression was NOT the
// occupancy theory failing: __launch_bounds__(256,4) forced VGPR 80->64
// against a ~140-float live set (v[40]+uh[40]+acc[40]) -> scratch spill
// (FETCH 19->141MB, WRITE 41->85MB; "VALUBusy 62%" was spill movs).
// Fix: launch_bounds(256,2) (the only config proven spill-free, VGPR~80)
// with PPB=8 / GRID=1024 -> 4 blocks/CU (grid-capped; VGPR 80 would allow
// 6 waves/SIMD, LDS 20.6KB allows 7 blocks). 2x R11's resident waves ->
// 2x interleaved s_load chains per SIMD (~13% duty each).
// Mapping (R11): wave g=(h,oh), lane=b_l (BT=64). W slice per (p,wave)
// wave-uniform, pre-permuted contiguous by k_perm -> s_load operands, zero
// LDS/vector traffic for W. Single pass per p: uh/acc/v reg-resident,
// statically indexed. Softmax: 5 partial logits through dbuf lgx exchange
// (stride 5, conflict-free, one barrier per p), then all-10 softmax
// per-thread (redundant x4, cheap). v per-thread from sPrev (regs).
// s-reduce: arena stage (stride 161) -> coalesced fp32 atomics, 2 rounds.
// Passes: K<0>: s1=sum_p uhat; K<1>: v1=squash(.1*s1), lg2=uhat.v1 -> global,
// s2+=softmax(lg2)*uhat; K<2>: v2=squash(s2), lg3=lg2+uhat.v2, s3+=...;
// k_out: squash(s3).

#define Bn 256
#define Pn 2048
#define Cn 10
#define On 16
#define In 8
#define ROW 160
#define BT 64
#define PPB 8
#define TPB 256
#define NBT (Bn / BT)     // 4
#define NPT (Pn / PPB)    // 256
#define GRID (NBT * NPT)  // 1024 -> 4 blocks/CU

// ---- one-time W permutation: Wp[p][g][kc][o][i], g = h*2+oh.
// Per (p, wave) slice = 320 contiguous floats -> s_load friendly.
__global__ __launch_bounds__(256) void k_perm(const float* __restrict__ W,
                                              float* __restrict__ Wp) {
  const int p = blockIdx.x;
  const float* src = W + (size_t)p * 1280;
  float* dst = Wp + (size_t)p * 1280;
#pragma unroll
  for (int r = 0; r < 5; ++r) {
    const int w = threadIdx.x + 256 * r;
    const int g = w / 320, rm = w - 320 * g;
    const int kc = rm >> 6, r2 = rm & 63;
    const int o = r2 >> 3, i = r2 & 7;
    const int h = g >> 1, oh = g & 1;
    dst[w] = src[((h * 5 + kc) * 16 + oh * 8 + o) * 8 + i];
  }
}

template <int MODE>
__global__ __launch_bounds__(TPB, 2) void k_cap(const float* __restrict__ u,
                                                const float* __restrict__ Wp,
                                                const float* __restrict__ sPrev,
                                                float* __restrict__ sOut,
                                                float* __restrict__ lg) {
  // arena: main loop = lgx[2][4g][64b][5] (2560 floats); tail = sAcc[32][161]
  __shared__ float arena[32 * 161]; // 20608 B -> LDS never the occupancy cap
  const int x = blockIdx.x;
  const int bt = x >> 8;   // 4 b-tiles
  const int pt = x & 255;  // 256 p-tiles; bt-sharers of a p-tile on one XCD
  const int tid = threadIdx.x;
  const int g = __builtin_amdgcn_readfirstlane(tid >> 6); // wave id = h*2+oh
  const int h = g >> 1, oh = g & 1;
  const int b_l = tid & 63;
  const int b = bt * BT + b_l;
  const int p0 = pt * PPB;

  // wave-uniform W base -> scalar loads
  const float* wp_s = Wp + ((size_t)p0 * 4 + g) * 320;

  // ---- v slice in registers (per-thread squash of sPrev; once per dispatch)
  float v[5][8];
  if (MODE >= 1) {
    const float scale = (MODE == 1) ? 0.1f : 1.0f;
    const float4* sp = reinterpret_cast<const float4*>(sPrev + (size_t)b * ROW);
#pragma unroll
    for (int kc = 0; kc < 5; ++kc) {
      const int c = h * 5 + kc;
      const float4 q0 = sp[c * 4 + 0], q1 = sp[c * 4 + 1];
      const float4 q2 = sp[c * 4 + 2], q3 = sp[c * 4 + 3];
      float sq = q0.x * q0.x + q0.y * q0.y + q0.z * q0.z + q0.w * q0.w;
      sq += q1.x * q1.x + q1.y * q1.y + q1.z * q1.z + q1.w * q1.w;
      sq += q2.x * q2.x + q2.y * q2.y + q2.z * q2.z + q2.w * q2.w;
      sq += q3.x * q3.x + q3.y * q3.y + q3.z * q3.z + q3.w * q3.w;
      sq *= scale * scale;
      const float fac = scale * (sq / (1.f + sq)) / sqrtf(sq + 1e-9f);
      const float4 qa = oh ? q2 : q0;
      const float4 qb = oh ? q3 : q1;
      v[kc][0] = fac * qa.x; v[kc][1] = fac * qa.y;
      v[kc][2] = fac * qa.z; v[kc][3] = fac * qa.w;
      v[kc][4] = fac * qb.x; v[kc][5] = fac * qb.y;
      v[kc][6] = fac * qb.z; v[kc][7] = fac * qb.w;
    }
  }

  float acc[5][8];
#pragma unroll
  for (int kc = 0; kc < 5; ++kc)
#pragma unroll
    for (int o = 0; o < 8; ++o) acc[kc][o] = 0.f;

  const float* urow = u + ((size_t)b * Pn + p0) * In;
  float4 cua, cub;
  {
    const float4* up = reinterpret_cast<const float4*>(urow);
    cua = up[0];
    cub = up[1];
  }

  for (int ip = 0; ip < PPB; ++ip) {
    // prefetch next p's u (named regs, static)
    float4 nua = cua, nub = cub;
    if (ip + 1 < PPB) {
      const float4* up = reinterpret_cast<const float4*>(urow + (ip + 1) * In);
      nua = up[0];
      nub = up[1];
    }
    const int p = p0 + ip;
    float lf[10];
    if (MODE == 2) { // issue early; latency hides under the dot block
      const float* lrow = lg + ((size_t)p * Bn + b) * Cn;
#pragma unroll
      for (int c = 0; c < 10; ++c) lf[c] = lrow[c];
    } else if (MODE == 1) {
#pragma unroll
      for (int c = 0; c < 10; ++c) lf[c] = 0.f;
    }
    const float uu[8] = {cua.x, cua.y, cua.z, cua.w, cub.x, cub.y, cub.z, cub.w};
    const float* wq = wp_s + ip * 1280; // scalar pointer

    float uh[5][8];
#pragma unroll
    for (int kc = 0; kc < 5; ++kc)
#pragma unroll
      for (int o = 0; o < 8; ++o) {
        const float* w8 = wq + kc * 64 + o * 8; // s_load operands
        float d = w8[0] * uu[0];
#pragma unroll
        for (int i = 1; i < 8; ++i) d = __builtin_fmaf(w8[i], uu[i], d);
        uh[kc][o] = d;
      }

    if (MODE == 0) {
#pragma unroll
      for (int kc = 0; kc < 5; ++kc)
#pragma unroll
        for (int o = 0; o < 8; ++o) acc[kc][o] += uh[kc][o];
    } else {
      // partial logits for this (h,oh) quarter
      float lp[5];
#pragma unroll
      for (int kc = 0; kc < 5; ++kc) {
        float ls = 0.f;
#pragma unroll
        for (int o = 0; o < 8; ++o) ls = __builtin_fmaf(uh[kc][o], v[kc][o], ls);
        lp[kc] = ls;
      }
      // exchange: lgx[(ip&1)][g][b_l][5]; stride 5 -> conflict-free
      float* lx = arena + (ip & 1) * 1280;
#pragma unroll
      for (int kc = 0; kc < 5; ++kc) lx[(g * 64 + b_l) * 5 + kc] = lp[kc];
      __syncthreads(); // double-buffered -> one barrier per p
#pragma unroll
      for (int c = 0; c < 10; ++c) {
        const int hh = c / 5, cc = c - 5 * (c / 5); // static after unroll
        lf[c] += lx[((hh * 2 + 0) * 64 + b_l) * 5 + cc] +
                 lx[((hh * 2 + 1) * 64 + b_l) * 5 + cc];
      }
      if (MODE == 1) {
        if (g == 0) { // wave-uniform branch; coalesced 40B/lane
          float* lrow = lg + ((size_t)p * Bn + b) * Cn;
#pragma unroll
          for (int c = 0; c < 10; ++c) lrow[c] = lf[c];
        }
      }
      // softmax over all 10 in-thread (redundant x4, cheap)
      float m = lf[0];
#pragma unroll
      for (int c = 1; c < 10; ++c) m = fmaxf(m, lf[c]);
      float ss = 0.f;
#pragma unroll
      for (int c = 0; c < 10; ++c) {
        lf[c] = __expf(lf[c] - m);
        ss += lf[c];
      }
      const float inv = 1.f / ss;
#pragma unroll
      for (int kc = 0; kc < 5; ++kc) {
        const float cv = lf[h * 5 + kc] * inv;
#pragma unroll
        for (int o = 0; o < 8; ++o)
          acc[kc][o] = __builtin_fmaf(cv, uh[kc][o], acc[kc][o]);
      }
    }
    cua = nua;
    cub = nub;
  }

  // ---- tail: 2 rounds of 32 b: stage (stride 161, conflict-free) + atomics
  __syncthreads(); // last lgx reads done before arena reuse
  float* sA = arena;
#pragma unroll
  for (int rnd = 0; rnd < 2; ++rnd) {
    if ((b_l >> 5) == rnd) {
      const int bl = b_l & 31;
#pragma unroll
      for (int kc = 0; kc < 5; ++kc)
#pragma unroll
        for (int o = 0; o < 8; ++o)
          sA[bl * 161 + (h * 5 + kc) * 16 + oh * 8 + o] = acc[kc][o];
    }
    __syncthreads();
#pragma unroll
    for (int r = 0; r < 20; ++r) {
      const int gi = tid + 256 * r; // 5120 cells, consecutive addresses
      const int bl = gi / 160, rem = gi - 160 * bl;
      atomicAdd(&sOut[(size_t)(bt * BT + rnd * 32 + bl) * ROW + rem],
                sA[bl * 161 + rem]);
    }
    if (rnd == 0) __syncthreads(); // reads done before round-1 overwrites
  }
}

__global__ __launch_bounds__(256) void k_out(const float* __restrict__ s,
                                             float* __restrict__ out) {
  const int gi = blockIdx.x * 256 + threadIdx.x; // [0, 2560) = (b,c)
  const int b = gi / 10, c = gi - 10 * b;
  const float* sp = s + (size_t)b * ROW + c * 16;
  float sq = 0.f;
#pragma unroll
  for (int o = 0; o < On; ++o) { const float xx = sp[o]; sq += xx * xx; }
  const float fac = (sq / (1.f + sq)) / sqrtf(sq + 1e-9f);
  float* op = out + (size_t)b * ROW + c * 16;
#pragma unroll
  for (int o = 0; o < On; ++o) op[o] = fac * sp[o];
}

extern "C" void kernel_launch(void* const* d_in, const int* in_sizes, int n_in,
                              void* d_out, int out_size, void* d_ws, size_t ws_size,
                              hipStream_t stream) {
  (void)in_sizes; (void)n_in; (void)out_size;
  const float* u = (const float*)d_in[0];
  const float* W = (const float*)d_in[1];
  float* out = (float*)d_out;
  float* s1 = (float*)d_ws;              // [256][160] fp32
  float* s2 = s1 + (size_t)Bn * ROW;
  float* s3 = s2 + (size_t)Bn * ROW;
  float* lg = s3 + (size_t)Bn * ROW;     // [2048][256][10] fp32, 21MB
  float* Wp = lg + (size_t)Pn * Bn * Cn; // permuted W, 10.5MB
  const size_t need = ((size_t)3 * Bn * ROW + (size_t)Pn * Bn * Cn +
                       (size_t)Pn * Cn * On * In) * sizeof(float);
  if (ws_size < need) return;
  hipMemsetAsync(d_ws, 0, (size_t)3 * Bn * ROW * sizeof(float), stream);
  k_perm<<<Pn, 256, 0, stream>>>(W, Wp);
  k_cap<0><<<GRID, TPB, 0, stream>>>(u, Wp, s1, s1, lg);
  k_cap<1><<<GRID, TPB, 0, stream>>>(u, Wp, s1, s2, lg);
  k_cap<2><<<GRID, TPB, 0, stream>>>(u, Wp, s2, s3, lg);
  k_out<<<10, 256, 0, stream>>>(s3, out);
}

// Round 8
// 204.644 us; speedup vs baseline: 2.2081x; 1.4973x over previous
//
#include <hip/hip_runtime.h>
#include <hip/hip_fp16.h>

// CapsNet dynamic routing, B=256, P=2048, C=10, OUT=16, IN=8, 3 iters.
// R14: fp16 LDS-broadcast W. R11/R13 evidence: __launch_bounds__ 2nd arg PINS
// blocks/CU (2 -> 8 waves/CU, R12's 4 -> VGPR 64 clamp -> spill), so with a
// ~120-float live set occupancy is stuck at 2 waves/SIMD. The scalar-pipe W
// (20 s_load_dwordx16/p through ~60 free SGPRs) serializes -> 9% wave duty,
// VALUBusy 17%. Fix the DUTY, not the occupancy: W pre-permuted to fp16
// (k_perm), staged ONCE per block into LDS (16p x 640B/slice = 40KB, gl_lds
// width-16, one barrier), then read as wave-uniform ds_read_b128 BROADCASTS
// (one b128 = 8 halves = one (kc,o) row; 40/p/wave; conflict-free by
// construction) feeding v_dot2_f32_f16 (160/p). ds reads pipeline deeply via
// lgkmcnt (unlike the serial scalar chains). uh kept PACKED half2 (20 regs,
// not 40) so live ~120 fits the (256,2) 128-reg cap: lg dot via fdot2
// against packed v (20 regs), acc += cv*uh via mixed-precision fma.
// fp16 W/u/uh rounding == R0-R7's fp16-uhat error scale (passed).
// PPB=16/GRID=512: exactly the 2 blocks/CU we're pinned at, halved fixed
// costs (v-prep, tail atomics: WRITE ~41MB).
// Mapping (R11): wave g=(h,oh), lane=b_l (BT=64). Softmax: partial logits
// through dbuf lgx (stride 5, conflict-free, 1 barrier/p; 0 in MODE0), then
// all-10 softmax per-thread. s-reduce: arena stage (stride 161) -> coalesced
// fp32 atomics.
// Passes: K<0>: s1=sum_p uhat; K<1>: v1=squash(.1*s1), lg2=uhat.v1 -> global,
// s2+=softmax(lg2)*uhat; K<2>: v2=squash(s2), lg3=lg2+uhat.v2, s3+=...;
// k_out: squash(s3).

#define Bn 256
#define Pn 2048
#define Cn 10
#define On 16
#define In 8
#define ROW 160
#define BT 64
#define PPB 16
#define TPB 256
#define NBT (Bn / BT)     // 4
#define NPT (Pn / PPB)    // 128
#define GRID (NBT * NPT)  // 512 -> 2 blocks/CU (the pinned residency)

typedef _Float16 h2f __attribute__((ext_vector_type(2)));
union WU { float4 f; h2f h[4]; };

__device__ __forceinline__ void gl_lds16(const void* g, void* l) {
  __builtin_amdgcn_global_load_lds(
      (const __attribute__((address_space(1))) unsigned int*)g,
      (__attribute__((address_space(3))) unsigned int*)l, 16, 0, 0);
}

__device__ __forceinline__ h2f pack2(float a, float b) {
  __half2 t = __floats2half2_rn(a, b);
  return *reinterpret_cast<h2f*>(&t);
}

__device__ __forceinline__ float dot8h(const WU w, h2f u0, h2f u1, h2f u2,
                                       h2f u3, float c) {
  c = __builtin_amdgcn_fdot2(w.h[0], u0, c, false);
  c = __builtin_amdgcn_fdot2(w.h[1], u1, c, false);
  c = __builtin_amdgcn_fdot2(w.h[2], u2, c, false);
  c = __builtin_amdgcn_fdot2(w.h[3], u3, c, false);
  return c;
}

// ---- one-time W permutation+cast: Wh[p][g][kc][o][i] half, g = h*2+oh.
// Per (p,g) slice = 320 contiguous halves; one (kc,o) row = 16B = 1 b128.
__global__ __launch_bounds__(256) void k_perm(const float* __restrict__ W,
                                              __half* __restrict__ Wh) {
  const int p = blockIdx.x;
  const float* src = W + (size_t)p * 1280;
  __half* dst = Wh + (size_t)p * 1280;
#pragma unroll
  for (int r = 0; r < 5; ++r) {
    const int w = threadIdx.x + 256 * r;
    const int g = w / 320, rm = w - 320 * g;
    const int kc = rm >> 6, r2 = rm & 63;
    const int o = r2 >> 3, i = r2 & 7;
    const int h = g >> 1, oh = g & 1;
    dst[w] = __float2half(src[((h * 5 + kc) * 16 + oh * 8 + o) * 8 + i]);
  }
}

template <int MODE>
__global__ __launch_bounds__(TPB, 2) void k_cap(const float* __restrict__ u,
                                                const __half* __restrict__ Wh,
                                                const float* __restrict__ sPrev,
                                                float* __restrict__ sOut,
                                                float* __restrict__ lg) {
  // arena: [0,10240) floats = wH (fp16, 16p*1280 halves = 40960B);
  //        [10240,12800) = lgx dbuf (2*1280 floats). Tail sAcc[32][161]
  //        (20608B) reuses the wH region. Total 51200B -> LDS allows 3.
  __shared__ float arena[12800];
  __half* wH = reinterpret_cast<__half*>(arena);
  float* lgx = arena + 10240;
  const int x = blockIdx.x;
  const int bt = x >> 7;   // 4 b-tiles
  const int pt = x & 127;  // 128 p-tiles; bt-sharers of a p-tile on one XCD
  const int tid = threadIdx.x;
  const int g = __builtin_amdgcn_readfirstlane(tid >> 6); // wave id = h*2+oh
  const int h = g >> 1, oh = g & 1;
  const int b_l = tid & 63;
  const int b = bt * BT + b_l;
  const int p0 = pt * PPB;

  // ---- stage this block's W (fp16, 40960B) via async DMA; 10 rounds x 16B
  {
    const char* ws = reinterpret_cast<const char*>(Wh + (size_t)p0 * 1280);
    char* wd = reinterpret_cast<char*>(wH);
#pragma unroll
    for (int r = 0; r < 10; ++r)
      gl_lds16(ws + r * 4096 + tid * 16, wd + r * 4096 + tid * 16);
  }

  // ---- v slice, packed half2 (per-thread squash of sPrev); overlaps DMA
  h2f vh[5][4];
  if (MODE >= 1) {
    const float scale = (MODE == 1) ? 0.1f : 1.0f;
    const float4* sp = reinterpret_cast<const float4*>(sPrev + (size_t)b * ROW);
#pragma unroll
    for (int kc = 0; kc < 5; ++kc) {
      const int c = h * 5 + kc;
      const float4 q0 = sp[c * 4 + 0], q1 = sp[c * 4 + 1];
      const float4 q2 = sp[c * 4 + 2], q3 = sp[c * 4 + 3];
      float sq = q0.x * q0.x + q0.y * q0.y + q0.z * q0.z + q0.w * q0.w;
      sq += q1.x * q1.x + q1.y * q1.y + q1.z * q1.z + q1.w * q1.w;
      sq += q2.x * q2.x + q2.y * q2.y + q2.z * q2.z + q2.w * q2.w;
      sq += q3.x * q3.x + q3.y * q3.y + q3.z * q3.z + q3.w * q3.w;
      sq *= scale * scale;
      const float fac = scale * (sq / (1.f + sq)) / sqrtf(sq + 1e-9f);
      const float4 qa = oh ? q2 : q0;
      const float4 qb = oh ? q3 : q1;
      vh[kc][0] = pack2(fac * qa.x, fac * qa.y);
      vh[kc][1] = pack2(fac * qa.z, fac * qa.w);
      vh[kc][2] = pack2(fac * qb.x, fac * qb.y);
      vh[kc][3] = pack2(fac * qb.z, fac * qb.w);
    }
  }
  __syncthreads(); // drains DMA (vmcnt) -> wH ready

  float acc[5][8];
#pragma unroll
  for (int kc = 0; kc < 5; ++kc)
#pragma unroll
    for (int o = 0; o < 8; ++o) acc[kc][o] = 0.f;

  const float* urow = u + ((size_t)b * Pn + p0) * In;
  float4 cua, cub;
  {
    const float4* up = reinterpret_cast<const float4*>(urow);
    cua = up[0];
    cub = up[1];
  }

  for (int ip = 0; ip < PPB; ++ip) {
    float4 nua = cua, nub = cub;
    if (ip + 1 < PPB) { // u prefetch (named regs)
      const float4* up = reinterpret_cast<const float4*>(urow + (ip + 1) * In);
      nua = up[0];
      nub = up[1];
    }
    const h2f u0 = pack2(cua.x, cua.y), u1 = pack2(cua.z, cua.w);
    const h2f u2 = pack2(cub.x, cub.y), u3 = pack2(cub.z, cub.w);
    // wave-uniform slice base -> broadcast b128 reads, one per (kc,o)
    const WU* wq = reinterpret_cast<const WU*>(wH + ((size_t)ip * 4 + g) * 320);

    if (MODE == 0) {
#pragma unroll
      for (int kc = 0; kc < 5; ++kc)
#pragma unroll
        for (int o = 0; o < 8; ++o)
          acc[kc][o] = dot8h(wq[kc * 8 + o], u0, u1, u2, u3, acc[kc][o]);
    } else {
      const int p = p0 + ip;
      float lf[10];
      if (MODE == 2) { // issue early; latency hides under the dot block
        const float* lrow = lg + ((size_t)p * Bn + b) * Cn;
#pragma unroll
        for (int c = 0; c < 10; ++c) lf[c] = lrow[c];
      } else {
#pragma unroll
        for (int c = 0; c < 10; ++c) lf[c] = 0.f;
      }
      h2f uhh[5][4];
      float* lx = lgx + (ip & 1) * 1280;
#pragma unroll
      for (int kc = 0; kc < 5; ++kc) {
#pragma unroll
        for (int o2 = 0; o2 < 4; ++o2) {
          const float d0 = dot8h(wq[kc * 8 + 2 * o2], u0, u1, u2, u3, 0.f);
          const float d1 = dot8h(wq[kc * 8 + 2 * o2 + 1], u0, u1, u2, u3, 0.f);
          uhh[kc][o2] = pack2(d0, d1);
        }
        float lp = __builtin_amdgcn_fdot2(uhh[kc][0], vh[kc][0], 0.f, false);
        lp = __builtin_amdgcn_fdot2(uhh[kc][1], vh[kc][1], lp, false);
        lp = __builtin_amdgcn_fdot2(uhh[kc][2], vh[kc][2], lp, false);
        lp = __builtin_amdgcn_fdot2(uhh[kc][3], vh[kc][3], lp, false);
        lx[(g * 64 + b_l) * 5 + kc] = lp; // stride 5 -> conflict-free
      }
      __syncthreads(); // double-buffered -> one barrier per p
#pragma unroll
      for (int c = 0; c < 10; ++c) {
        const int hh = c / 5, cc = c - 5 * (c / 5); // static after unroll
        lf[c] += lx[((hh * 2 + 0) * 64 + b_l) * 5 + cc] +
                 lx[((hh * 2 + 1) * 64 + b_l) * 5 + cc];
      }
      if (MODE == 1) {
        if (g == 0) { // wave-uniform branch; coalesced 40B/lane
          float* lrow = lg + ((size_t)p * Bn + b) * Cn;
#pragma unroll
          for (int c = 0; c < 10; ++c) lrow[c] = lf[c];
        }
      }
      // softmax over all 10 in-thread (redundant x4, cheap)
      float m = lf[0];
#pragma unroll
      for (int c = 1; c < 10; ++c) m = fmaxf(m, lf[c]);
      float ss = 0.f;
#pragma unroll
      for (int c = 0; c < 10; ++c) {
        lf[c] = __expf(lf[c] - m);
        ss += lf[c];
      }
      const float inv = 1.f / ss;
#pragma unroll
      for (int kc = 0; kc < 5; ++kc) {
        const float cv = lf[h * 5 + kc] * inv;
#pragma unroll
        for (int o2 = 0; o2 < 4; ++o2) { // mixed-precision fma (v_fma_mix)
          acc[kc][2 * o2] =
              __builtin_fmaf(cv, (float)uhh[kc][o2][0], acc[kc][2 * o2]);
          acc[kc][2 * o2 + 1] =
              __builtin_fmaf(cv, (float)uhh[kc][o2][1], acc[kc][2 * o2 + 1]);
        }
      }
    }
    cua = nua;
    cub = nub;
  }

  // ---- tail: 2 rounds of 32 b: stage (stride 161, conflict-free) + atomics
  __syncthreads(); // last lgx reads done before arena reuse
  float* sA = arena;
#pragma unroll
  for (int rnd = 0; rnd < 2; ++rnd) {
    if ((b_l >> 5) == rnd) {
      const int bl = b_l & 31;
#pragma unroll
      for (int kc = 0; kc < 5; ++kc)
#pragma unroll
        for (int o = 0; o < 8; ++o)
          sA[bl * 161 + (h * 5 + kc) * 16 + oh * 8 + o] = acc[kc][o];
    }
    __syncthreads();
#pragma unroll
    for (int r = 0; r < 20; ++r) {
      const int gi = tid + 256 * r; // 5120 cells, consecutive addresses
      const int bl = gi / 160, rem = gi - 160 * bl;
      atomicAdd(&sOut[(size_t)(bt * BT + rnd * 32 + bl) * ROW + rem],
                sA[bl * 161 + rem]);
    }
    if (rnd == 0) __syncthreads(); // reads done before round-1 overwrites
  }
}

__global__ __launch_bounds__(256) void k_out(const float* __restrict__ s,
                                             float* __restrict__ out) {
  const int gi = blockIdx.x * 256 + threadIdx.x; // [0, 2560) = (b,c)
  const int b = gi / 10, c = gi - 10 * b;
  const float* sp = s + (size_t)b * ROW + c * 16;
  float sq = 0.f;
#pragma unroll
  for (int o = 0; o < On; ++o) { const float xx = sp[o]; sq += xx * xx; }
  const float fac = (sq / (1.f + sq)) / sqrtf(sq + 1e-9f);
  float* op = out + (size_t)b * ROW + c * 16;
#pragma unroll
  for (int o = 0; o < On; ++o) op[o] = fac * sp[o];
}

extern "C" void kernel_launch(void* const* d_in, const int* in_sizes, int n_in,
                              void* d_out, int out_size, void* d_ws, size_t ws_size,
                              hipStream_t stream) {
  (void)in_sizes; (void)n_in; (void)out_size;
  const float* u = (const float*)d_in[0];
  const float* W = (const float*)d_in[1];
  float* out = (float*)d_out;
  float* s1 = (float*)d_ws;              // [256][160] fp32
  float* s2 = s1 + (size_t)Bn * ROW;
  float* s3 = s2 + (size_t)Bn * ROW;
  float* lg = s3 + (size_t)Bn * ROW;     // [2048][256][10] fp32, 21MB
  __half* Wh = reinterpret_cast<__half*>(lg + (size_t)Pn * Bn * Cn); // 5.25MB
  const size_t need = ((size_t)3 * Bn * ROW + (size_t)Pn * Bn * Cn) * sizeof(float) +
                      (size_t)Pn * Cn * On * In * sizeof(__half);
  if (ws_size < need) return;
  hipMemsetAsync(d_ws, 0, (size_t)3 * Bn * ROW * sizeof(float), stream);
  k_perm<<<Pn, 256, 0, stream>>>(W, Wh);
  k_cap<0><<<GRID, TPB, 0, stream>>>(u, Wh, s1, s1, lg);
  k_cap<1><<<GRID, TPB, 0, stream>>>(u, Wh, s1, s2, lg);
  k_cap<2><<<GRID, TPB, 0, stream>>>(u, Wh, s2, s3, lg);
  k_out<<<10, 256, 0, stream>>>(s3, out);
}